// Round 2
// baseline (2208.173 us; speedup 1.0000x reference)
//
#include <hip/hip_runtime.h>
#include <math.h>

#define B_IMG 64
#define H_ 64
#define W_ 64
#define L_ (H_*W_)
#define C_ 96
#define WSZ 8
#define SSZ 4
#define NH_ 4
#define HD_ 24
#define NT_ 64

// ---------------- Kernel 1: LN1 + shifted-window attention + proj + residual ----------------
// one block per window; window token (i,j) of window (wh,ww) maps bijectively to
// original pixel ((wh*8+i+4)&63, (ww*8+j+4)&63)  (cyclic shift fused into addressing)
__global__ __launch_bounds__(256)
void k_attn(const float* __restrict__ x,
            const float* __restrict__ g1, const float* __restrict__ b1,
            const float* __restrict__ qkvw, const float* __restrict__ qkvb,
            const float* __restrict__ rpbt,
            const float* __restrict__ projw, const float* __restrict__ projb,
            float* __restrict__ xmid)
{
    const int wid = blockIdx.x;          // 0..4095 = b*64 + wh*8 + ww
    const int b   = wid >> 6;
    const int whi = (wid >> 3) & 7;
    const int wwi = wid & 7;
    const int tid = threadIdx.x;

    __shared__ float hbuf[NT_][C_+4];        // LN output (64x100); reused as 64x64 score matrix
    __shared__ float qkvs[12][NT_][HD_+1];   // [s*4+h][n][d]  (q region later reused for o)
    __shared__ float rpb[225*NH_];
    __shared__ float gv[C_], bv[C_];
    __shared__ int   regid[NT_];

    // ---- P0: stage small tables + mask region ids ----
    for (int i = tid; i < 225*NH_; i += 256) rpb[i] = rpbt[i];
    if (tid < C_) { gv[tid] = g1[tid]; bv[tid] = b1[tid]; }
    if (tid < NT_) {
        const int i = tid >> 3, j = tid & 7;
        const int rh = (whi == 7) ? ((i < SSZ) ? 1 : 2) : 0;
        const int rw = (wwi == 7) ? ((j < SSZ) ? 1 : 2) : 0;
        regid[tid] = rh*3 + rw;
    }
    __syncthreads();

    // ---- P1: LayerNorm -> hbuf ----
    {
        const int tok = tid >> 2, q = tid & 3;
        const int i = tok >> 3, j = tok & 7;
        const int sr = (whi*WSZ + i + SSZ) & (H_-1);
        const int sc = (wwi*WSZ + j + SSZ) & (W_-1);
        const float* row = x + ((size_t)b*L_ + sr*W_ + sc) * C_;
        float v[24];
        float s = 0.f, s2 = 0.f;
#pragma unroll
        for (int m = 0; m < 6; ++m) {
            float4 f = ((const float4*)row)[q + 4*m];
            v[4*m+0]=f.x; v[4*m+1]=f.y; v[4*m+2]=f.z; v[4*m+3]=f.w;
            s  += f.x+f.y+f.z+f.w;
            s2 += f.x*f.x+f.y*f.y+f.z*f.z+f.w*f.w;
        }
        s  += __shfl_xor(s, 1);  s  += __shfl_xor(s, 2);
        s2 += __shfl_xor(s2, 1); s2 += __shfl_xor(s2, 2);
        const float mu = s * (1.f/96.f);
        const float rstd = rsqrtf(s2*(1.f/96.f) - mu*mu + 1e-5f);
#pragma unroll
        for (int m = 0; m < 6; ++m)
#pragma unroll
            for (int e = 0; e < 4; ++e) {
                const int c = 4*(q + 4*m) + e;
                hbuf[tok][c] = (v[4*m+e]-mu)*rstd*gv[c] + bv[c];
            }
    }
    __syncthreads();

    // ---- P2: QKV GEMM -> qkvs[g][n][d], g = s*4+h, oc = g*24+d ----
    {
        const int sub  = tid & 63;
        const int gpar = tid >> 6;           // 0..3 (one wave per group)
        const int tg   = sub >> 2;           // token group: 4 tokens
        const int dg   = sub & 3;            // d group: 6 d's
#pragma unroll
        for (int it = 0; it < 3; ++it) {
            const int g = gpar*3 + it;       // 0..11
            float acc[4][6];
#pragma unroll
            for (int r=0;r<4;++r)
#pragma unroll
                for (int m=0;m<6;++m) acc[r][m] = 0.f;
            const float* wbase = qkvw + (size_t)(g*24 + dg*6)*96;
            for (int k = 0; k < 96; k += 4) {
                float4 a4[4];
#pragma unroll
                for (int r=0;r<4;++r) a4[r] = *(const float4*)&hbuf[tg*4+r][k];
#pragma unroll
                for (int m=0;m<6;++m) {
                    const float4 w4 = *(const float4*)(wbase + m*96 + k);
#pragma unroll
                    for (int r=0;r<4;++r)
                        acc[r][m] += a4[r].x*w4.x + a4[r].y*w4.y + a4[r].z*w4.z + a4[r].w*w4.w;
                }
            }
#pragma unroll
            for (int m=0;m<6;++m) {
                const float bb = qkvb[g*24 + dg*6 + m];
#pragma unroll
                for (int r=0;r<4;++r)
                    qkvs[g][tg*4+r][dg*6+m] = acc[r][m] + bb;
            }
        }
    }
    __syncthreads();

    const float scale = 0.20412414523193154f;   // 24^-0.5

    // ---- P3: per-head attention ----
    for (int h = 0; h < NH_; ++h) {
        // scores + scale + rel-pos bias + shift mask -> hbuf[n1][n2]
        {
            const int n1g = tid >> 4;        // 0..15 -> 4 rows
            const int n2g = tid & 15;        // 0..15 -> 4 cols
            float acc[4][4];
#pragma unroll
            for (int r=0;r<4;++r)
#pragma unroll
                for (int c=0;c<4;++c) acc[r][c] = 0.f;
            for (int d = 0; d < HD_; ++d) {
                float qv[4], kv[4];
#pragma unroll
                for (int r=0;r<4;++r) qv[r] = qkvs[h][n1g*4+r][d];
#pragma unroll
                for (int c=0;c<4;++c) kv[c] = qkvs[4+h][n2g*4+c][d];
#pragma unroll
                for (int r=0;r<4;++r)
#pragma unroll
                    for (int c=0;c<4;++c) acc[r][c] += qv[r]*kv[c];
            }
#pragma unroll
            for (int r=0;r<4;++r) {
                const int n1 = n1g*4+r;
                const int i1 = n1>>3, j1 = n1&7;
#pragma unroll
                for (int c=0;c<4;++c) {
                    const int n2 = n2g*4+c;
                    const int i2 = n2>>3, j2 = n2&7;
                    const int idx = (i1-i2+7)*15 + (j1-j2+7);
                    float sv = acc[r][c]*scale + rpb[idx*NH_ + h];
                    if (regid[n1] != regid[n2]) sv -= 100.f;
                    hbuf[n1][n2] = sv;
                }
            }
        }
        __syncthreads();
        // softmax over rows
        {
            const int tok = tid >> 2, q = tid & 3;
            float v[16];
            float mx = -1e30f;
#pragma unroll
            for (int m=0;m<16;++m) { v[m] = hbuf[tok][q*16+m]; mx = fmaxf(mx, v[m]); }
            mx = fmaxf(mx, __shfl_xor(mx,1)); mx = fmaxf(mx, __shfl_xor(mx,2));
            float sm = 0.f;
#pragma unroll
            for (int m=0;m<16;++m) { v[m] = __expf(v[m]-mx); sm += v[m]; }
            sm += __shfl_xor(sm,1); sm += __shfl_xor(sm,2);
            const float inv = 1.f/sm;
#pragma unroll
            for (int m=0;m<16;++m) hbuf[tok][q*16+m] = v[m]*inv;
        }
        __syncthreads();
        // PV -> overwrite q-region qkvs[h][n][d] with o
        {
            const int dsub = tid >> 5;       // 0..7 -> d = dsub*3..+2
            const int n1   = (tid & 31)*2;   // 2 rows
            float acc[2][3];
#pragma unroll
            for (int r=0;r<2;++r)
#pragma unroll
                for (int e=0;e<3;++e) acc[r][e] = 0.f;
            for (int n2 = 0; n2 < NT_; ++n2) {
                const float p0 = hbuf[n1][n2], p1 = hbuf[n1+1][n2];
                const float v0 = qkvs[8+h][n2][dsub*3+0];
                const float v1 = qkvs[8+h][n2][dsub*3+1];
                const float v2 = qkvs[8+h][n2][dsub*3+2];
                acc[0][0] += p0*v0; acc[0][1] += p0*v1; acc[0][2] += p0*v2;
                acc[1][0] += p1*v0; acc[1][1] += p1*v1; acc[1][2] += p1*v2;
            }
#pragma unroll
            for (int r=0;r<2;++r)
#pragma unroll
                for (int e=0;e<3;++e) qkvs[h][n1+r][dsub*3+e] = acc[r][e];
        }
        __syncthreads();
    }

    // ---- P4: proj + residual + scatter back through shift ----
    {
        const int cg = tid >> 4;             // 0..15 -> c2 = cg*6..+5
        const int ng = tid & 15;             // -> n = ng*4..+3
        float acc[4][6];
#pragma unroll
        for (int r=0;r<4;++r)
#pragma unroll
            for (int m=0;m<6;++m) acc[r][m] = 0.f;
#pragma unroll
        for (int hh = 0; hh < 4; ++hh) {
            for (int dd = 0; dd < 24; dd += 4) {
                float a[4][4];
#pragma unroll
                for (int r=0;r<4;++r)
#pragma unroll
                    for (int e=0;e<4;++e) a[r][e] = qkvs[hh][ng*4+r][dd+e];
                const int k = hh*24+dd;
#pragma unroll
                for (int m=0;m<6;++m) {
                    const float4 w4 = *(const float4*)(projw + (size_t)(cg*6+m)*96 + k);
#pragma unroll
                    for (int r=0;r<4;++r)
                        acc[r][m] += a[r][0]*w4.x + a[r][1]*w4.y + a[r][2]*w4.z + a[r][3]*w4.w;
                }
            }
        }
#pragma unroll
        for (int r=0;r<4;++r) {
            const int n = ng*4+r;
            const int i = n>>3, j = n&7;
            const int sr = (whi*WSZ + i + SSZ) & (H_-1);
            const int sc = (wwi*WSZ + j + SSZ) & (W_-1);
            const float* xr = x    + ((size_t)b*L_ + sr*W_ + sc)*C_;
            float*      orow = xmid + ((size_t)b*L_ + sr*W_ + sc)*C_;
#pragma unroll
            for (int m=0;m<6;++m) {
                const int c = cg*6+m;
                orow[c] = acc[r][m] + projb[c] + xr[c];
            }
        }
    }
}

// ---------------- Kernel 2: LN2 + fc1 + GELU + fc2 + residual (in-place on xio) ----------------
// NOTE: xio is read (LN2 + residual) and written (final out) by the SAME pointer on
// purpose: per address, the only writer is the thread that also did the residual read,
// and the LN2 reads are separated from the writes by two __syncthreads(). No __restrict__.
__global__ __launch_bounds__(256)
void k_mlp(float* xio,
           const float* __restrict__ g2, const float* __restrict__ b2,
           const float* __restrict__ w1, const float* __restrict__ bb1,
           const float* __restrict__ w2, const float* __restrict__ bb2)
{
    const int r0 = blockIdx.x * 32;
    const int tid = threadIdx.x;

    __shared__ float hrow[32][C_+4];   // 12.8 KB
    __shared__ float h1[32][388];      // 49.7 KB
    __shared__ float gv[C_], bv[C_];

    if (tid < C_) { gv[tid] = g2[tid]; bv[tid] = b2[tid]; }
    __syncthreads();

    // LN2 (8 threads per row)
    {
        const int rr = tid >> 3, q = tid & 7;
        const float* row = xio + (size_t)(r0+rr)*C_;
        float v[12];
        float s = 0.f, s2 = 0.f;
#pragma unroll
        for (int m = 0; m < 3; ++m) {
            float4 f = ((const float4*)row)[q + 8*m];
            v[4*m+0]=f.x; v[4*m+1]=f.y; v[4*m+2]=f.z; v[4*m+3]=f.w;
            s  += f.x+f.y+f.z+f.w;
            s2 += f.x*f.x+f.y*f.y+f.z*f.z+f.w*f.w;
        }
        s  += __shfl_xor(s, 1);  s  += __shfl_xor(s, 2);  s  += __shfl_xor(s, 4);
        s2 += __shfl_xor(s2, 1); s2 += __shfl_xor(s2, 2); s2 += __shfl_xor(s2, 4);
        const float mu = s * (1.f/96.f);
        const float rstd = rsqrtf(s2*(1.f/96.f) - mu*mu + 1e-5f);
#pragma unroll
        for (int m = 0; m < 3; ++m)
#pragma unroll
            for (int e = 0; e < 4; ++e) {
                const int c = 4*(q + 8*m) + e;
                hrow[rr][c] = (v[4*m+e]-mu)*rstd*gv[c] + bv[c];
            }
    }
    __syncthreads();

    // fc1 + exact GELU -> h1   (tile 4 rows x 6 hidden)
    {
        const int rg = tid & 7;            // rows rg*4..+3
        const int hg = tid >> 3;           // 0..31
#pragma unroll
        for (int it = 0; it < 2; ++it) {
            const int h0 = it*192 + hg*6;
            float acc[4][6];
#pragma unroll
            for (int r=0;r<4;++r)
#pragma unroll
                for (int m=0;m<6;++m) acc[r][m] = 0.f;
            for (int k = 0; k < 96; k += 4) {
                float4 a4[4];
#pragma unroll
                for (int r=0;r<4;++r) a4[r] = *(const float4*)&hrow[rg*4+r][k];
#pragma unroll
                for (int m=0;m<6;++m) {
                    const float4 w4 = *(const float4*)(w1 + (size_t)(h0+m)*96 + k);
#pragma unroll
                    for (int r=0;r<4;++r)
                        acc[r][m] += a4[r].x*w4.x + a4[r].y*w4.y + a4[r].z*w4.z + a4[r].w*w4.w;
                }
            }
#pragma unroll
            for (int m=0;m<6;++m) {
                const float bias = bb1[h0+m];
#pragma unroll
                for (int r=0;r<4;++r) {
                    const float t = acc[r][m] + bias;
                    h1[rg*4+r][h0+m] = 0.5f*t*(1.f + erff(t*0.70710678118654752f));
                }
            }
        }
    }
    __syncthreads();

    // fc2 + residual -> xio  (tile 4 rows x 3 cols)
    {
        const int rg = tid & 7;            // rows rg*4..+3
        const int cg = tid >> 3;           // c = cg*3..+2
        float acc[4][3];
#pragma unroll
        for (int r=0;r<4;++r)
#pragma unroll
            for (int m=0;m<3;++m) acc[r][m] = 0.f;
        for (int k = 0; k < 384; k += 4) {
            float4 a4[4];
#pragma unroll
            for (int r=0;r<4;++r) a4[r] = *(const float4*)&h1[rg*4+r][k];
#pragma unroll
            for (int m=0;m<3;++m) {
                const float4 w4 = *(const float4*)(w2 + (size_t)(cg*3+m)*384 + k);
#pragma unroll
                for (int r=0;r<4;++r)
                    acc[r][m] += a4[r].x*w4.x + a4[r].y*w4.y + a4[r].z*w4.z + a4[r].w*w4.w;
            }
        }
#pragma unroll
        for (int r=0;r<4;++r) {
            const int row = r0 + rg*4 + r;
            float* rowp = xio + (size_t)row*C_;
#pragma unroll
            for (int m=0;m<3;++m) {
                const int c = cg*3+m;
                const float res = rowp[c];           // residual read (same thread)
                rowp[c] = acc[r][m] + bb2[c] + res;  // then write
            }
        }
    }
}

extern "C" void kernel_launch(void* const* d_in, const int* in_sizes, int n_in,
                              void* d_out, int out_size, void* d_ws, size_t ws_size,
                              hipStream_t stream) {
    const float* x    = (const float*)d_in[0];
    const float* n1g  = (const float*)d_in[1];
    const float* n1b  = (const float*)d_in[2];
    const float* qkvw = (const float*)d_in[3];
    const float* qkvb = (const float*)d_in[4];
    const float* rpbt = (const float*)d_in[5];
    const float* pw   = (const float*)d_in[6];
    const float* pb   = (const float*)d_in[7];
    const float* n2g  = (const float*)d_in[8];
    const float* n2b  = (const float*)d_in[9];
    const float* w1   = (const float*)d_in[10];
    const float* b1f  = (const float*)d_in[11];
    const float* w2   = (const float*)d_in[12];
    const float* b2f  = (const float*)d_in[13];
    float* outp = (float*)d_out;

    // K1: per-window attention block, writes x_mid = shortcut + attn(LN1(x))
    k_attn<<<dim3(4096), dim3(256), 0, stream>>>(x, n1g, n1b, qkvw, qkvb, rpbt, pw, pb, outp);
    // K2: in-place MLP block: out = x_mid + fc2(gelu(fc1(LN2(x_mid))))
    k_mlp<<<dim3(8192), dim3(256), 0, stream>>>(outp, n2g, n2b, w1, b1f, w2, b2f);
}